// Round 5
// baseline (7083.195 us; speedup 1.0000x reference)
//
#include <hip/hip_runtime.h>
#include <hip/hip_cooperative_groups.h>
#include <hip/hip_bf16.h>
#include <math.h>

namespace cg = cooperative_groups;

#define Bb 1024
#define Tt 15
#define Ii 256
#define Hh 512
#define Ff 8
#define Gg 2048  // 4*Hh

typedef __attribute__((ext_vector_type(8))) short short8v;
typedef __attribute__((ext_vector_type(4))) float f32x4;

__device__ __forceinline__ float sigmoidf_(float x) { return 1.0f / (1.0f + expf(-x)); }
__device__ __forceinline__ float bf2f(unsigned short u) {
    return __uint_as_float(((unsigned int)u) << 16);
}
__device__ __forceinline__ unsigned short f2bf(float f) {
    unsigned int u = __float_as_uint(f);
    u += 0x7fffu + ((u >> 16) & 1u);   // RNE
    return (unsigned short)(u >> 16);
}

// ---------------- fp32 -> bf16 plain (X) ----------------
__global__ __launch_bounds__(256) void cvt_kernel(const float* __restrict__ in,
                                                  unsigned short* __restrict__ out, int n8) {
    const int i = blockIdx.x * 256 + threadIdx.x;
    if (i < n8) {
        const float4 v0 = ((const float4*)in)[i * 2];
        const float4 v1 = ((const float4*)in)[i * 2 + 1];
        union { unsigned short u[8]; short8v v; } ob;
        ob.u[0] = f2bf(v0.x); ob.u[1] = f2bf(v0.y); ob.u[2] = f2bf(v0.z); ob.u[3] = f2bf(v0.w);
        ob.u[4] = f2bf(v1.x); ob.u[5] = f2bf(v1.y); ob.u[6] = f2bf(v1.z); ob.u[7] = f2bf(v1.w);
        *(short8v*)&out[(size_t)i * 8] = ob.v;
    }
}

// ---------------- fp32 -> bf16 with per-row chunk XOR swizzle (weights) ----------------
// chunk c (8 elems) of row r is stored at chunk position c ^ (r & 7).
__global__ __launch_bounds__(256) void cvt_wswz_kernel(const float* __restrict__ in,
                                                       unsigned short* __restrict__ out,
                                                       int Kc, int nchunks) {
    const int i = blockIdx.x * 256 + threadIdx.x;
    if (i < nchunks) {
        const int row = i / Kc, c = i % Kc;
        const float4 v0 = ((const float4*)in)[(size_t)i * 2];
        const float4 v1 = ((const float4*)in)[(size_t)i * 2 + 1];
        union { unsigned short u[8]; short8v v; } ob;
        ob.u[0] = f2bf(v0.x); ob.u[1] = f2bf(v0.y); ob.u[2] = f2bf(v0.z); ob.u[3] = f2bf(v0.w);
        ob.u[4] = f2bf(v1.x); ob.u[5] = f2bf(v1.y); ob.u[6] = f2bf(v1.z); ob.u[7] = f2bf(v1.w);
        *(short8v*)&out[((size_t)row * Kc + (c ^ (row & 7))) * 8] = ob.v;
    }
}

// ---------------- GEMM tile: C[1024 x 64] += A[1024 x K] * Wlds^T ----------------
// Wave owns 64 batch rows (m0). B frags from swizzled LDS; A frags straight from global.
template<int KX>
__device__ __forceinline__ void gemm_tile(
    const short* __restrict__ a0, long s0,
    const short* __restrict__ a1, long s1,
    const short* sW, int lane, int m0, f32x4 (&acc)[4][4])
{
    constexpr int KXc = KX >> 3;
    constexpr int KTc = KXc + 64;            // chunks per LDS row
    const int al = lane & 15;
    const int ak = (lane >> 4) * 8;
    const int bx = lane & 7;

    for (int kb = 0; kb < KX; kb += 32) {
        short8v av[4], bv[4];
#pragma unroll
        for (int i = 0; i < 4; ++i)
            av[i] = *(const short8v*)(a0 + (size_t)(m0 + i * 16 + al) * s0 + kb + ak);
#pragma unroll
        for (int j = 0; j < 4; ++j)
            bv[j] = *(const short8v*)&sW[(size_t)(j * 16 + al) * (KTc * 8)
                                         + (size_t)((((kb >> 3) + (lane >> 4)) ^ bx) << 3)];
#pragma unroll
        for (int i = 0; i < 4; ++i)
#pragma unroll
            for (int j = 0; j < 4; ++j)
                acc[i][j] = __builtin_amdgcn_mfma_f32_16x16x32_bf16(av[i], bv[j], acc[i][j], 0, 0, 0);
    }
    if (a1) {
        for (int kb = 0; kb < Hh; kb += 32) {
            short8v av[4], bv[4];
#pragma unroll
            for (int i = 0; i < 4; ++i)
                av[i] = *(const short8v*)(a1 + (size_t)(m0 + i * 16 + al) * s1 + kb + ak);
#pragma unroll
            for (int j = 0; j < 4; ++j)
                bv[j] = *(const short8v*)&sW[(size_t)(j * 16 + al) * (KTc * 8)
                                             + (size_t)((KXc + ((((kb >> 3) + (lane >> 4)) ^ bx))) << 3)];
#pragma unroll
            for (int i = 0; i < 4; ++i)
#pragma unroll
                for (int j = 0; j < 4; ++j)
                    acc[i][j] = __builtin_amdgcn_mfma_f32_16x16x32_bf16(av[i], bv[j], acc[i][j], 0, 0, 0);
        }
    }
}

// ---------------- persistent LSTM: both layers + proj + BN partials ----------------
// grid = 256 blocks (f = blockIdx&7 -> XCD-local), 1024 threads (16 waves x 64-row M slices).
// Block (f,hs) owns gate rows {g*512 + hs*16 + 0..15} in LDS for the whole kernel; cell
// state lives in registers. One grid.sync per timestep.
__global__ __launch_bounds__(1024) void lstm_persistent(
    const short* __restrict__ Xbf,
    const short* __restrict__ W0x, const short* __restrict__ W0h,
    const short* __restrict__ W1x, const short* __restrict__ W1h,
    const short* __restrict__ A1s,
    const float* __restrict__ b0p, const float* __restrict__ b1p,
    const float* __restrict__ c1v,
    short* __restrict__ ybuf, short* __restrict__ h1A, short* __restrict__ h1B,
    float* __restrict__ part)
{
    const int f  = blockIdx.x & 7;
    const int hs = blockIdx.x >> 3;
    const int h0 = hs * 16;
    const int tid = threadIdx.x;
    const int wave = tid >> 6, lane = tid & 63;
    const int m0 = wave * 64;
    const int al = lane & 15;
    const int ak = (lane >> 4) * 8;
    const int bx = lane & 7;

    __shared__ __align__(16) short sW[64 * 1024];   // 128 KB
    __shared__ __align__(16) short sA1[16 * 512];   // 16 KB
    __shared__ float red[32];

    cg::grid_group grid = cg::this_grid();

    // stage A1 o-slice [16][512] once (global already swizzled; copy is linear)
    for (int q = tid; q < 16 * 64; q += 1024) {
        const int r = q >> 6, c = q & 63;
        *(short8v*)&sA1[(size_t)(r * 64 + c) * 8] =
            *(const short8v*)&A1s[(size_t)(h0 + r) * Hh + (size_t)c * 8];
    }

    auto stageW = [&](const short* Wx, const short* Wh, int KX) {
        const int KXc = KX >> 3, KTc = KXc + 64;
        for (int q = tid; q < 64 * KTc; q += 1024) {
            const int r = q / KTc, c = q % KTc;
            const int R = (r >> 4) * Hh + h0 + (r & 15);
            short8v v;
            if (c < KXc) v = *(const short8v*)&Wx[((size_t)f * Gg + R) * KX + (size_t)c * 8];
            else         v = *(const short8v*)&Wh[((size_t)f * Gg + R) * Hh + (size_t)(c - KXc) * 8];
            *(short8v*)&sW[(size_t)r * (KTc * 8) + (size_t)c * 8] = v;
        }
    };

    stageW(W0x, W0h, Ii);
    __syncthreads();

    float bj[4];
#pragma unroll
    for (int g = 0; g < 4; ++g) bj[g] = b0p[(size_t)f * Gg + g * Hh + h0 + al];

    float cst[4][4];

    // ---------------- layer 0 ----------------
    for (int t = 0; t < Tt; ++t) {
        f32x4 acc[4][4] = {};
        gemm_tile<Ii>(Xbf + (size_t)t * Ii, (long)Tt * Ii,
                      t ? ybuf + ((size_t)f * Bb * Tt + (t - 1)) * Hh : nullptr, (long)Tt * Hh,
                      sW, lane, m0, acc);
#pragma unroll
        for (int i = 0; i < 4; ++i)
#pragma unroll
            for (int r = 0; r < 4; ++r) {
                const float gi = acc[i][0][r] + bj[0];
                const float gf = acc[i][1][r] + bj[1];
                const float gg = acc[i][2][r] + bj[2];
                const float go = acc[i][3][r] + bj[3];
                const float cold = t ? cst[i][r] : 0.f;
                const float cn = sigmoidf_(gf) * cold + sigmoidf_(gi) * tanhf(gg);
                cst[i][r] = cn;
                const float hv = sigmoidf_(go) * tanhf(cn);
                const int b = m0 + i * 16 + (lane >> 4) * 4 + r;
                ((unsigned short*)ybuf)[(((size_t)f * Bb + b) * Tt + t) * Hh + h0 + al] = f2bf(hv);
            }
        __threadfence();
        grid.sync();
    }

    // ---------------- reload weights for layer 1 ----------------
    stageW(W1x, W1h, Hh);
    __syncthreads();
#pragma unroll
    for (int g = 0; g < 4; ++g) bj[g] = b1p[(size_t)f * Gg + g * Hh + h0 + al];
    const float c1o = c1v[h0 + al];

    // ---------------- layer 1 + proj + BN partials ----------------
    for (int t = 0; t < Tt; ++t) {
        short* hw = (t & 1) ? h1A : h1B;
        const short* hr = (t & 1) ? h1B : h1A;
        f32x4 acc[4][4] = {};
        gemm_tile<Hh>(ybuf + ((size_t)f * Bb * Tt + t) * Hh, (long)Tt * Hh,
                      t ? hr + (size_t)f * Bb * Hh : nullptr, (long)Hh,
                      sW, lane, m0, acc);
#pragma unroll
        for (int i = 0; i < 4; ++i)
#pragma unroll
            for (int r = 0; r < 4; ++r) {
                const float gi = acc[i][0][r] + bj[0];
                const float gf = acc[i][1][r] + bj[1];
                const float gg = acc[i][2][r] + bj[2];
                const float go = acc[i][3][r] + bj[3];
                const float cold = t ? cst[i][r] : 0.f;
                const float cn = sigmoidf_(gf) * cold + sigmoidf_(gi) * tanhf(gg);
                cst[i][r] = cn;
                const float hv = sigmoidf_(go) * tanhf(cn);
                const int b = m0 + i * 16 + (lane >> 4) * 4 + r;
                ((unsigned short*)hw)[((size_t)f * Bb + b) * Hh + h0 + al] = f2bf(hv);
            }
        __threadfence();
        grid.sync();

        // proj: C[1024 x 16] = h1[t] @ A1[o-slice]^T  (overwrites consumed ybuf slice t)
        f32x4 p[4] = {};
        const short* ha = hw + (size_t)f * Bb * Hh;
        for (int kb = 0; kb < Hh; kb += 32) {
            short8v av[4];
#pragma unroll
            for (int i = 0; i < 4; ++i)
                av[i] = *(const short8v*)(ha + (size_t)(m0 + i * 16 + al) * Hh + kb + ak);
            const short8v bvp = *(const short8v*)&sA1[(size_t)al * 512
                                 + (size_t)((((kb >> 3) + (lane >> 4)) ^ bx) << 3)];
#pragma unroll
            for (int i = 0; i < 4; ++i)
                p[i] = __builtin_amdgcn_mfma_f32_16x16x32_bf16(av[i], bvp, p[i], 0, 0, 0);
        }
        float ss = 0.f, sq = 0.f;
#pragma unroll
        for (int i = 0; i < 4; ++i)
#pragma unroll
            for (int r = 0; r < 4; ++r) {
                const unsigned short hb = f2bf(p[i][r] + c1o);
                const float fv = bf2f(hb);
                ss += fv; sq += fv * fv;
                const int b = m0 + i * 16 + (lane >> 4) * 4 + r;
                ((unsigned short*)ybuf)[(((size_t)f * Bb + b) * Tt + t) * Hh + h0 + al] = hb;
            }
#pragma unroll
        for (int o2 = 32; o2 > 0; o2 >>= 1) {
            ss += __shfl_down(ss, o2);
            sq += __shfl_down(sq, o2);
        }
        if (lane == 0) { red[wave * 2] = ss; red[wave * 2 + 1] = sq; }
        __syncthreads();
        if (tid == 0) {
            float S = 0.f, Q = 0.f;
#pragma unroll
            for (int w = 0; w < 16; ++w) { S += red[w * 2]; Q += red[w * 2 + 1]; }
            const size_t pi = ((size_t)f * Tt + t) * 32 + hs;
            part[pi * 2] = S; part[pi * 2 + 1] = Q;
        }
        __syncthreads();
    }
}

// ---------------- stats combine: mean / rsqrt(var) per (f,t) from 32 partials ----------------
__global__ void stats_combine_kernel(const float* __restrict__ part, float* __restrict__ stats)
{
    const int i = threadIdx.x;
    if (i < Ff * Tt) {
        float s = 0.f, q = 0.f;
        for (int j = 0; j < 32; ++j) { s += part[(i * 32 + j) * 2]; q += part[(i * 32 + j) * 2 + 1]; }
        const float n = (float)((size_t)Bb * Hh);
        const float mean = s / n;
        const float var  = q / n - mean * mean;
        stats[i * 2]     = mean;
        stats[i * 2 + 1] = rsqrtf(var + 1e-5f);
    }
}

// ---------------- Output: out[b,t,f] = sum_o relu(bn(htmp)) * A2[o] + c2 ----------------
__global__ __launch_bounds__(256) void out_kernel(
    const unsigned short* __restrict__ htmp, const float* __restrict__ stats,
    const float* __restrict__ gamma, const float* __restrict__ beta,
    const float* __restrict__ A2, const float* __restrict__ c2,
    float* __restrict__ out)
{
    const int wave = threadIdx.x >> 6;
    const int lane = threadIdx.x & 63;
    const size_t row = (size_t)blockIdx.x * 4 + wave;   // (f*B + b)*T + t
    const int t = (int)(row % Tt);
    const size_t fb = row / Tt;
    const int b = (int)(fb % Bb);
    const int f = (int)(fb / Bb);

    const float mean = stats[(f * Tt + t) * 2];
    const float inv  = stats[(f * Tt + t) * 2 + 1];
    const float ga = gamma[t], be = beta[t];
    const unsigned short* hrow = htmp + row * Hh;

    union { float4 f4; unsigned short u[8]; } hv;
    hv.f4 = *(const float4*)(hrow + lane * 8);
    const float4 a0 = *(const float4*)(A2 + lane * 8);
    const float4 a1 = *(const float4*)(A2 + lane * 8 + 4);
    const float a2v[8] = {a0.x, a0.y, a0.z, a0.w, a1.x, a1.y, a1.z, a1.w};

    float acc = 0.f;
#pragma unroll
    for (int j = 0; j < 8; ++j) {
        const float x = (bf2f(hv.u[j]) - mean) * inv * ga + be;
        acc += fmaxf(x, 0.f) * a2v[j];
    }
#pragma unroll
    for (int off = 32; off > 0; off >>= 1) acc += __shfl_down(acc, off);
    if (lane == 0) out[(size_t)b * Tt * Ff + (size_t)t * Ff + f] = acc + c2[0];
}

extern "C" void kernel_launch(void* const* d_in, const int* in_sizes, int n_in,
                              void* d_out, int out_size, void* d_ws, size_t ws_size,
                              hipStream_t stream) {
    const float* X     = (const float*)d_in[0];
    const float* Wih0  = (const float*)d_in[1];
    const float* Whh0  = (const float*)d_in[2];
    const float* b0p   = (const float*)d_in[3];
    const float* Wih1  = (const float*)d_in[4];
    const float* Whh1  = (const float*)d_in[5];
    const float* b1p   = (const float*)d_in[6];
    const float* A1    = (const float*)d_in[7];
    const float* c1v   = (const float*)d_in[8];
    const float* gamma = (const float*)d_in[9];
    const float* beta  = (const float*)d_in[10];
    const float* A2    = (const float*)d_in[11];
    const float* c2    = (const float*)d_in[12];
    float* out = (float*)d_out;

    // ---- workspace layout (~210 MiB) ----
    char* ws = (char*)d_ws;
    size_t off = 0;
    short* Xbf  = (short*)(ws + off); off += (size_t)Bb * Tt * Ii * 2;
    short* W0x  = (short*)(ws + off); off += (size_t)Ff * Gg * Ii * 2;
    short* W0h  = (short*)(ws + off); off += (size_t)Ff * Gg * Hh * 2;
    short* W1x  = (short*)(ws + off); off += (size_t)Ff * Gg * Hh * 2;
    short* W1h  = (short*)(ws + off); off += (size_t)Ff * Gg * Hh * 2;
    short* A1s  = (short*)(ws + off); off += (size_t)Hh * Hh * 2;
    short* ybuf = (short*)(ws + off); off += (size_t)Ff * Bb * Tt * Hh * 2;
    short* h1A  = (short*)(ws + off); off += (size_t)Ff * Bb * Hh * 2;
    short* h1B  = (short*)(ws + off); off += (size_t)Ff * Bb * Hh * 2;
    float* part = (float*)(ws + off); off += (size_t)Ff * Tt * 32 * 2 * 4;
    float* stats = (float*)(ws + off); off += (size_t)Ff * Tt * 2 * 4;

    const dim3 blk(256);
    // converts (weights pre-swizzled per-row for LDS bank-conflict-free ds_read_b128)
    cvt_kernel<<<dim3((Bb * Tt * Ii / 8 + 255) / 256), blk, 0, stream>>>(
        X, (unsigned short*)Xbf, Bb * Tt * Ii / 8);
    cvt_wswz_kernel<<<dim3((Ff * Gg * Ii / 8 + 255) / 256), blk, 0, stream>>>(
        Wih0, (unsigned short*)W0x, Ii / 8, Ff * Gg * Ii / 8);
    cvt_wswz_kernel<<<dim3((Ff * Gg * Hh / 8 + 255) / 256), blk, 0, stream>>>(
        Whh0, (unsigned short*)W0h, Hh / 8, Ff * Gg * Hh / 8);
    cvt_wswz_kernel<<<dim3((Ff * Gg * Hh / 8 + 255) / 256), blk, 0, stream>>>(
        Wih1, (unsigned short*)W1x, Hh / 8, Ff * Gg * Hh / 8);
    cvt_wswz_kernel<<<dim3((Ff * Gg * Hh / 8 + 255) / 256), blk, 0, stream>>>(
        Whh1, (unsigned short*)W1h, Hh / 8, Ff * Gg * Hh / 8);
    cvt_wswz_kernel<<<dim3((Hh * Hh / 8 + 255) / 256), blk, 0, stream>>>(
        A1, (unsigned short*)A1s, Hh / 8, Hh * Hh / 8);

    // persistent cooperative kernel: 256 blocks x 1024 threads
    void* args[] = {
        (void*)&Xbf, (void*)&W0x, (void*)&W0h, (void*)&W1x, (void*)&W1h, (void*)&A1s,
        (void*)&b0p, (void*)&b1p, (void*)&c1v,
        (void*)&ybuf, (void*)&h1A, (void*)&h1B, (void*)&part
    };
    hipLaunchCooperativeKernel((void*)lstm_persistent, dim3(Ff * 32), dim3(1024),
                               args, 0, stream);

    stats_combine_kernel<<<dim3(1), dim3(128), 0, stream>>>(part, stats);
    out_kernel<<<dim3(Ff * Bb * Tt / 4), blk, 0, stream>>>((const unsigned short*)ybuf, stats,
        gamma, beta, A2, c2, out);
    (void)in_sizes; (void)n_in; (void)out_size; (void)ws_size;
}

// Round 6
// 1666.067 us; speedup vs baseline: 4.2514x; 4.2514x over previous
//
#include <hip/hip_runtime.h>
#include <hip/hip_bf16.h>
#include <math.h>

#define Bb 1024
#define Tt 15
#define Ii 256
#define Hh 512
#define Ff 8
#define Gg 2048  // 4*Hh

typedef __attribute__((ext_vector_type(8))) short short8v;
typedef __attribute__((ext_vector_type(4))) float f32x4;

typedef const __attribute__((address_space(1))) void* gas_ptr;
typedef __attribute__((address_space(3))) void* las_ptr;

__device__ __forceinline__ float sigmoidf_(float x) { return 1.0f / (1.0f + expf(-x)); }
__device__ __forceinline__ float bf2f(unsigned short u) {
    return __uint_as_float(((unsigned int)u) << 16);
}
__device__ __forceinline__ unsigned short f2bf(float f) {
    unsigned int u = __float_as_uint(f);
    u += 0x7fffu + ((u >> 16) & 1u);   // RNE
    return (unsigned short)(u >> 16);
}

// ---------------- fp32 -> bf16 conversion (n8 = n/8) ----------------
__global__ __launch_bounds__(256) void cvt_kernel(const float* __restrict__ in,
                                                  unsigned short* __restrict__ out, int n8) {
    const int i = blockIdx.x * 256 + threadIdx.x;
    if (i < n8) {
        const float4 v0 = ((const float4*)in)[i * 2];
        const float4 v1 = ((const float4*)in)[i * 2 + 1];
        union { unsigned short u[8]; short8v v; } ob;
        ob.u[0] = f2bf(v0.x); ob.u[1] = f2bf(v0.y); ob.u[2] = f2bf(v0.z); ob.u[3] = f2bf(v0.w);
        ob.u[4] = f2bf(v1.x); ob.u[5] = f2bf(v1.y); ob.u[6] = f2bf(v1.z); ob.u[7] = f2bf(v1.w);
        *(short8v*)&out[(size_t)i * 8] = ob.v;
    }
}

// ---------------- MFMA step kernel (double-buffered counted-vmcnt pipeline) ----------------
// grid = (Ff, h-blocks, Bb/128): blockIdx.x = f -> per-XCD weight residency.
// MODE 0: layer-0 LSTM step; MODE 1: layer-1 LSTM step; MODE 2: proj (+BN partial stats).
// Tile 128 (batch) x 128 (cols). 4 waves. BK=64, 2 LDS buffers; x-phase and h-phase fused
// into one continuous K pipeline. Per wave per tile: 8 global_load_lds(16B) ->
// steady-state s_waitcnt vmcnt(8), raw s_barrier (no vmcnt(0) drain in main loop).
template<int MODE, bool FIRST>
__global__ __launch_bounds__(256) void step_mfma(
    const short* Xbf, const short* ysrc, short* ydst,
    const short* hsrc, short* hdst,
    const short* __restrict__ Wx, const short* __restrict__ Wh,
    const float* __restrict__ bias, float* __restrict__ cbuf,
    unsigned short* htmp, float* __restrict__ part, int t)
{
    constexpr bool WG = (MODE != 2);                 // gate-structured W rows
    constexpr int KX = (MODE == 0) ? Ii : Hh;
    constexpr int NX = KX / 64;
    constexpr int NT = FIRST ? NX : ((MODE == 2) ? NX : NX + Hh / 64);

    const int f  = blockIdx.x;
    const int h0 = blockIdx.y * ((MODE == 2) ? 128 : 32);
    const int b0 = blockIdx.z * 128;
    const int tid = threadIdx.x;
    const int wave = tid >> 6, lane = tid & 63;
    const int wm = (wave >> 1) * 64, wn = (wave & 1) * 64;

    __shared__ __align__(16) char smem[65600];
    short* sStage = (short*)smem;             // 2 bufs x (A 8192 + B 8192 shorts)
    float* gt = (float*)smem;                 // [32][132] f32 epilogue chunk (alias)
    float* pr = (float*)(smem + 65536);

    f32x4 acc[4][4];
#pragma unroll
    for (int i = 0; i < 4; ++i)
#pragma unroll
        for (int j = 0; j < 4; ++j) acc[i][j] = (f32x4){0.f, 0.f, 0.f, 0.f};

    // staging geometry: per gload_lds instr: 64 lanes x 16B = 1KB = 8 rows of 128B
    const int srow8 = lane >> 3;
    const int csrc  = (lane & 7) ^ srow8;          // pre-swizzled source chunk
    const int frow  = lane & 15, fks = lane >> 4;

    // -------- source descriptors --------
    const short* ax; long axs; const short* wxp;
    const short* ah = nullptr; long ahs = 0; const short* whp = nullptr;
    if constexpr (MODE == 0) {
        ax = Xbf + ((size_t)b0 * Tt + t) * Ii; axs = (long)Tt * Ii;
        wxp = Wx + (size_t)f * Gg * Ii;
        if (!FIRST) {
            ah = ysrc + (((size_t)f * Bb + b0) * Tt + (t - 1)) * Hh; ahs = (long)Tt * Hh;
            whp = Wh + (size_t)f * Gg * Hh;
        }
    } else if constexpr (MODE == 1) {
        ax = ysrc + (((size_t)f * Bb + b0) * Tt + t) * Hh; axs = (long)Tt * Hh;
        wxp = Wx + (size_t)f * Gg * Hh;
        if (!FIRST) {
            ah = hsrc + ((size_t)f * Bb + b0) * Hh; ahs = (long)Hh;
            whp = Wh + (size_t)f * Gg * Hh;
        }
    } else {
        ax = hsrc + ((size_t)f * Bb + b0) * Hh; axs = (long)Hh;
        wxp = Wx;
    }

    auto stage = [&](int it, int buf) {
        const short* abase; long as; const short* wbase; int K; int kb;
        if (it < NX) { abase = ax; as = axs; wbase = wxp; K = KX; kb = it * 64; }
        else         { abase = ah; as = ahs; wbase = whp; K = Hh; kb = (it - NX) * 64; }
        short* dA = sStage + buf * 16384;
        short* dB = dA + 8192;
#pragma unroll
        for (int i = 0; i < 4; ++i) {
            const int inst = wave * 4 + i;
            const int row = inst * 8 + srow8;
            const short* srcA = abase + (size_t)row * as + kb + csrc * 8;
            __builtin_amdgcn_global_load_lds((gas_ptr)(const void*)srcA,
                (las_ptr)(void*)(dA + inst * 512), 16, 0, 0);
            const int wr = WG ? ((row >> 5) * Hh + h0 + (row & 31)) : (h0 + row);
            const short* srcB = wbase + (size_t)wr * K + kb + csrc * 8;
            __builtin_amdgcn_global_load_lds((gas_ptr)(const void*)srcB,
                (las_ptr)(void*)(dB + inst * 512), 16, 0, 0);
        }
    };

    auto compute = [&](int buf) {
        const short* bA = sStage + buf * 16384;
        const short* bB = bA + 8192;
        __builtin_amdgcn_s_setprio(1);
#pragma unroll
        for (int ks = 0; ks < 2; ++ks) {
            short8v av[4], bv[4];
#pragma unroll
            for (int i = 0; i < 4; ++i) {
                const int r = wm + i * 16 + frow;
                av[i] = *(const short8v*)&bA[r * 64 + (((fks + ks * 4) ^ (r & 7)) * 8)];
            }
#pragma unroll
            for (int j = 0; j < 4; ++j) {
                const int r = wn + j * 16 + frow;
                bv[j] = *(const short8v*)&bB[r * 64 + (((fks + ks * 4) ^ (r & 7)) * 8)];
            }
#pragma unroll
            for (int i = 0; i < 4; ++i)
#pragma unroll
                for (int j = 0; j < 4; ++j)
                    acc[i][j] = __builtin_amdgcn_mfma_f32_16x16x32_bf16(av[i], bv[j], acc[i][j], 0, 0, 0);
        }
        __builtin_amdgcn_s_setprio(0);
    };

    // preload bias into regs and force materialization before the pipeline starts
    float bi[4] = {0.f, 0.f, 0.f, 0.f};
    if constexpr (MODE != 2) {
        const int hl = tid & 31;
#pragma unroll
        for (int g = 0; g < 4; ++g) bi[g] = bias[(size_t)f * Gg + g * Hh + h0 + hl];
        asm volatile("" : "+v"(bi[0]), "+v"(bi[1]), "+v"(bi[2]), "+v"(bi[3]));
    }

    // -------- pipelined K loop --------
    stage(0, 0);
    for (int it = 0; it < NT; ++it) {
        if (it + 1 < NT) {
            stage(it + 1, (it + 1) & 1);
            asm volatile("s_waitcnt vmcnt(8)" ::: "memory");
        } else {
            asm volatile("s_waitcnt vmcnt(0)" ::: "memory");
        }
        __builtin_amdgcn_s_barrier();
        __builtin_amdgcn_sched_barrier(0);
        compute(it & 1);
        __builtin_amdgcn_sched_barrier(0);
        __builtin_amdgcn_s_barrier();
    }

    // ---- chunked epilogue: 4 chunks of 32 rows through gt [32][132] f32 ----
    if constexpr (MODE != 2) {
        const int hl = tid & 31, bg = tid >> 5;
#pragma unroll
        for (int ch = 0; ch < 4; ++ch) {
            if ((wave >> 1) == (ch >> 1)) {
                const int i0 = (ch & 1) * 2;
#pragma unroll
                for (int i2 = 0; i2 < 2; ++i2) {
                    const int i = i0 + i2;
#pragma unroll
                    for (int j = 0; j < 4; ++j)
#pragma unroll
                        for (int r = 0; r < 4; ++r)
                            gt[(i2 * 16 + (lane >> 4) * 4 + r) * 132 + wn + j * 16 + (lane & 15)] = acc[i][j][r];
                }
            }
            __syncthreads();
#pragma unroll
            for (int ii = 0; ii < 4; ++ii) {
                const int rl = bg * 4 + ii;
                const int b = b0 + ch * 32 + rl;
                const float gi = gt[rl * 132 +      hl] + bi[0];
                const float gf = gt[rl * 132 + 32 + hl] + bi[1];
                const float gg = gt[rl * 132 + 64 + hl] + bi[2];
                const float go = gt[rl * 132 + 96 + hl] + bi[3];
                const size_t cidx = ((size_t)f * Bb + b) * Hh + h0 + hl;
                const float cold = FIRST ? 0.f : cbuf[cidx];
                const float cn = sigmoidf_(gf) * cold + sigmoidf_(gi) * tanhf(gg);
                const float hv = sigmoidf_(go) * tanhf(cn);
                cbuf[cidx] = cn;
                const unsigned short hb = f2bf(hv);
                if (MODE == 0)
                    ((unsigned short*)ydst)[(((size_t)f * Bb + b) * Tt + t) * Hh + h0 + hl] = hb;
                else
                    ((unsigned short*)hdst)[cidx] = hb;
            }
            __syncthreads();
        }
    } else {
        const int rr2 = tid >> 3, cb = (tid & 7) * 16;
        float ssum = 0.f, ssq = 0.f;
#pragma unroll
        for (int ch = 0; ch < 4; ++ch) {
            if ((wave >> 1) == (ch >> 1)) {
                const int i0 = (ch & 1) * 2;
#pragma unroll
                for (int i2 = 0; i2 < 2; ++i2) {
                    const int i = i0 + i2;
#pragma unroll
                    for (int j = 0; j < 4; ++j)
#pragma unroll
                        for (int r = 0; r < 4; ++r)
                            gt[(i2 * 16 + (lane >> 4) * 4 + r) * 132 + wn + j * 16 + (lane & 15)] = acc[i][j][r];
                }
            }
            __syncthreads();
            const int b = b0 + ch * 32 + rr2;
            union { unsigned short u[8]; short8v v; } o1, o2;
#pragma unroll
            for (int u = 0; u < 8; ++u) {
                const unsigned short hb = f2bf(gt[rr2 * 132 + cb + u] + bias[h0 + cb + u]);
                const float hv = bf2f(hb);
                ssum += hv; ssq += hv * hv;
                o1.u[u] = hb;
            }
#pragma unroll
            for (int u = 0; u < 8; ++u) {
                const unsigned short hb = f2bf(gt[rr2 * 132 + cb + 8 + u] + bias[h0 + cb + 8 + u]);
                const float hv = bf2f(hb);
                ssum += hv; ssq += hv * hv;
                o2.u[u] = hb;
            }
            unsigned short* dst = htmp + (((size_t)f * Bb + b) * Tt + t) * Hh + h0 + cb;
            *(short8v*)dst = o1.v;
            *(short8v*)(dst + 8) = o2.v;
            __syncthreads();
        }
        // block partial (sum, sumsq) for BN stats
#pragma unroll
        for (int off2 = 32; off2 > 0; off2 >>= 1) {
            ssum += __shfl_down(ssum, off2);
            ssq  += __shfl_down(ssq,  off2);
        }
        if (lane == 0) { pr[wave * 2] = ssum; pr[wave * 2 + 1] = ssq; }
        __syncthreads();
        if (tid == 0) {
            float S = 0.f, Q = 0.f;
#pragma unroll
            for (int w = 0; w < 4; ++w) { S += pr[w * 2]; Q += pr[w * 2 + 1]; }
            const size_t pi = (((size_t)f * Tt + t) * 4 + blockIdx.y) * 8 + blockIdx.z;
            part[pi * 2] = S; part[pi * 2 + 1] = Q;
        }
    }
}

// ---------------- stats combine: mean / rsqrt(var) per (f,t) from 32 partials ----------------
__global__ void stats_combine_kernel(const float* __restrict__ part, float* __restrict__ stats)
{
    const int i = threadIdx.x;
    if (i < Ff * Tt) {
        float s = 0.f, q = 0.f;
        for (int j = 0; j < 32; ++j) { s += part[(i * 32 + j) * 2]; q += part[(i * 32 + j) * 2 + 1]; }
        const float n = (float)((size_t)Bb * Hh);
        const float mean = s / n;
        const float var  = q / n - mean * mean;
        stats[i * 2]     = mean;
        stats[i * 2 + 1] = rsqrtf(var + 1e-5f);
    }
}

// ---------------- Output: out[b,t,f] = sum_o relu(bn(htmp)) * A2[o] + c2 ----------------
__global__ __launch_bounds__(256) void out_kernel(
    const unsigned short* __restrict__ htmp, const float* __restrict__ stats,
    const float* __restrict__ gamma, const float* __restrict__ beta,
    const float* __restrict__ A2, const float* __restrict__ c2,
    float* __restrict__ out)
{
    const int wave = threadIdx.x >> 6;
    const int lane = threadIdx.x & 63;
    const size_t row = (size_t)blockIdx.x * 4 + wave;   // (f*B + b)*T + t
    const int t = (int)(row % Tt);
    const size_t fb = row / Tt;
    const int b = (int)(fb % Bb);
    const int f = (int)(fb / Bb);

    const float mean = stats[(f * Tt + t) * 2];
    const float inv  = stats[(f * Tt + t) * 2 + 1];
    const float ga = gamma[t], be = beta[t];
    const unsigned short* hrow = htmp + row * Hh;

    union { float4 f4; unsigned short u[8]; } hv;
    hv.f4 = *(const float4*)(hrow + lane * 8);
    const float4 a0 = *(const float4*)(A2 + lane * 8);
    const float4 a1 = *(const float4*)(A2 + lane * 8 + 4);
    const float a2v[8] = {a0.x, a0.y, a0.z, a0.w, a1.x, a1.y, a1.z, a1.w};

    float acc = 0.f;
#pragma unroll
    for (int j = 0; j < 8; ++j) {
        const float x = (bf2f(hv.u[j]) - mean) * inv * ga + be;
        acc += fmaxf(x, 0.f) * a2v[j];
    }
#pragma unroll
    for (int off = 32; off > 0; off >>= 1) acc += __shfl_down(acc, off);
    if (lane == 0) out[(size_t)b * Tt * Ff + (size_t)t * Ff + f] = acc + c2[0];
}

extern "C" void kernel_launch(void* const* d_in, const int* in_sizes, int n_in,
                              void* d_out, int out_size, void* d_ws, size_t ws_size,
                              hipStream_t stream) {
    const float* X     = (const float*)d_in[0];
    const float* Wih0  = (const float*)d_in[1];
    const float* Whh0  = (const float*)d_in[2];
    const float* b0p   = (const float*)d_in[3];
    const float* Wih1  = (const float*)d_in[4];
    const float* Whh1  = (const float*)d_in[5];
    const float* b1p   = (const float*)d_in[6];
    const float* A1    = (const float*)d_in[7];
    const float* c1v   = (const float*)d_in[8];
    const float* gamma = (const float*)d_in[9];
    const float* beta  = (const float*)d_in[10];
    const float* A2    = (const float*)d_in[11];
    const float* c2    = (const float*)d_in[12];
    float* out = (float*)d_out;

    // ---- workspace layout (bytes), total ~216 MiB ----
    char* ws = (char*)d_ws;
    size_t off = 0;
    short* Xbf    = (short*)(ws + off); off += (size_t)Bb * Tt * Ii * 2;
    short* Wih0bf = (short*)(ws + off); off += (size_t)Ff * Gg * Ii * 2;
    short* Whh0bf = (short*)(ws + off); off += (size_t)Ff * Gg * Hh * 2;
    short* Wih1bf = (short*)(ws + off); off += (size_t)Ff * Gg * Hh * 2;
    short* Whh1bf = (short*)(ws + off); off += (size_t)Ff * Gg * Hh * 2;
    short* A1bf   = (short*)(ws + off); off += (size_t)Hh * Hh * 2;
    short* ybuf   = (short*)(ws + off); off += (size_t)Ff * Bb * Tt * Hh * 2;
    short* h1A    = (short*)(ws + off); off += (size_t)Ff * Bb * Hh * 2;
    short* h1B    = (short*)(ws + off); off += (size_t)Ff * Bb * Hh * 2;
    float* cbuf   = (float*)(ws + off); off += (size_t)Ff * Bb * Hh * 4;
    float* part   = (float*)(ws + off); off += (size_t)Ff * Tt * 32 * 2 * 4;
    float* stats  = (float*)(ws + off); off += (size_t)Ff * Tt * 2 * 4;

    const dim3 blk(256);
    cvt_kernel<<<dim3((Bb * Tt * Ii / 8 + 255) / 256), blk, 0, stream>>>(X, (unsigned short*)Xbf, Bb * Tt * Ii / 8);
    cvt_kernel<<<dim3((Ff * Gg * Ii / 8 + 255) / 256), blk, 0, stream>>>(Wih0, (unsigned short*)Wih0bf, Ff * Gg * Ii / 8);
    cvt_kernel<<<dim3((Ff * Gg * Hh / 8 + 255) / 256), blk, 0, stream>>>(Whh0, (unsigned short*)Whh0bf, Ff * Gg * Hh / 8);
    cvt_kernel<<<dim3((Ff * Gg * Hh / 8 + 255) / 256), blk, 0, stream>>>(Wih1, (unsigned short*)Wih1bf, Ff * Gg * Hh / 8);
    cvt_kernel<<<dim3((Ff * Gg * Hh / 8 + 255) / 256), blk, 0, stream>>>(Whh1, (unsigned short*)Whh1bf, Ff * Gg * Hh / 8);
    cvt_kernel<<<dim3((Hh * Hh / 8 + 255) / 256), blk, 0, stream>>>(A1, (unsigned short*)A1bf, Hh * Hh / 8);

    const dim3 gstep(Ff, Hh / 32, Bb / 128);   // f fastest -> per-XCD weight residency
    const dim3 gproj(Ff, Hh / 128, Bb / 128);

    // layer 0: all timesteps, writes ybuf[f,b,t,:]
    for (int t = 0; t < Tt; ++t) {
        if (t == 0)
            step_mfma<0, true><<<gstep, blk, 0, stream>>>(Xbf, ybuf, ybuf, nullptr, nullptr,
                Wih0bf, Whh0bf, b0p, cbuf, nullptr, part, t);
        else
            step_mfma<0, false><<<gstep, blk, 0, stream>>>(Xbf, ybuf, ybuf, nullptr, nullptr,
                Wih0bf, Whh0bf, b0p, cbuf, nullptr, part, t);
    }

    // layer 1 + proj: step t reads ybuf slice t; proj overwrites ybuf slice t (stream-ordered)
    for (int t = 0; t < Tt; ++t) {
        short* hn = (t & 1) ? h1A : h1B;
        short* hp = (t & 1) ? h1B : h1A;
        if (t == 0)
            step_mfma<1, true><<<gstep, blk, 0, stream>>>(nullptr, ybuf, nullptr, hp, hn,
                Wih1bf, Whh1bf, b1p, cbuf, nullptr, part, t);
        else
            step_mfma<1, false><<<gstep, blk, 0, stream>>>(nullptr, ybuf, nullptr, hp, hn,
                Wih1bf, Whh1bf, b1p, cbuf, nullptr, part, t);
        step_mfma<2, false><<<gproj, blk, 0, stream>>>(nullptr, nullptr, nullptr, hn, nullptr,
            A1bf, nullptr, c1v, cbuf, (unsigned short*)ybuf, part, t);
    }

    stats_combine_kernel<<<dim3(1), dim3(128), 0, stream>>>(part, stats);
    out_kernel<<<dim3(Ff * Bb * Tt / 4), blk, 0, stream>>>((const unsigned short*)ybuf, stats,
        gamma, beta, A2, c2, out);
    (void)in_sizes; (void)n_in; (void)out_size; (void)ws_size;
}

// Round 7
// 1622.501 us; speedup vs baseline: 4.3656x; 1.0269x over previous
//
#include <hip/hip_runtime.h>
#include <hip/hip_bf16.h>
#include <math.h>

#define Bb 1024
#define Tt 15
#define Ii 256
#define Hh 512
#define Ff 8
#define Gg 2048  // 4*Hh

typedef __attribute__((ext_vector_type(8))) short short8v;
typedef __attribute__((ext_vector_type(4))) float f32x4;

typedef const __attribute__((address_space(1))) void* gas_ptr;
typedef __attribute__((address_space(3))) void* las_ptr;

__device__ __forceinline__ float sigmoidf_(float x) {
    return __builtin_amdgcn_rcpf(1.0f + __expf(-x));
}
__device__ __forceinline__ float tanhf_(float x) {
    x = fminf(fmaxf(x, -15.0f), 15.0f);
    const float e = __expf(2.0f * x);
    return (e - 1.0f) * __builtin_amdgcn_rcpf(e + 1.0f);
}
__device__ __forceinline__ float bf2f(unsigned short u) {
    return __uint_as_float(((unsigned int)u) << 16);
}
__device__ __forceinline__ unsigned short f2bf(float f) {
    unsigned int u = __float_as_uint(f);
    u += 0x7fffu + ((u >> 16) & 1u);   // RNE
    return (unsigned short)(u >> 16);
}

// ---------------- fp32 -> bf16 conversion (n8 = n/8) ----------------
__global__ __launch_bounds__(256) void cvt_kernel(const float* __restrict__ in,
                                                  unsigned short* __restrict__ out, int n8) {
    const int i = blockIdx.x * 256 + threadIdx.x;
    if (i < n8) {
        const float4 v0 = ((const float4*)in)[i * 2];
        const float4 v1 = ((const float4*)in)[i * 2 + 1];
        union { unsigned short u[8]; short8v v; } ob;
        ob.u[0] = f2bf(v0.x); ob.u[1] = f2bf(v0.y); ob.u[2] = f2bf(v0.z); ob.u[3] = f2bf(v0.w);
        ob.u[4] = f2bf(v1.x); ob.u[5] = f2bf(v1.y); ob.u[6] = f2bf(v1.z); ob.u[7] = f2bf(v1.w);
        *(short8v*)&out[(size_t)i * 8] = ob.v;
    }
}

// ---------------- MFMA step kernel: BK=32, 3-buffer rotation, 1 barrier/tile ----------------
// grid = (Ff, h-blocks, Bb/128): blockIdx.x = f -> per-XCD weight residency.
// MODE 0: layer-0 LSTM step; MODE 1: layer-1 LSTM step; MODE 2: proj (+BN partial stats).
// Tile 128x128, 4 waves. LDS buf = 128 rows x 128B, row r = [A-row-r 64B | B-row-r 64B],
// chunk XOR-swizzled by (r&7) (same address function as the measured-0-conflict BK=64 layout).
// Loop: vmcnt(4) -> s_barrier -> stage(it+2 -> buf[(it+2)%3]) -> compute(buf[it%3]).
template<int MODE, bool FIRST>
__global__ __launch_bounds__(256) void step_mfma(
    const short* Xbf, const short* ysrc, short* ydst,
    const short* hsrc, short* hdst,
    const short* __restrict__ Wx, const short* __restrict__ Wh,
    const float* __restrict__ bias, float* __restrict__ cbuf,
    unsigned short* htmp, float* __restrict__ part, int t)
{
    constexpr bool WG = (MODE != 2);                 // gate-structured W rows
    constexpr int KX = (MODE == 0) ? Ii : Hh;
    constexpr int NX = KX / 32;
    constexpr int NT = FIRST ? NX : ((MODE == 2) ? NX : NX + Hh / 32);

    const int f  = blockIdx.x;
    const int h0 = blockIdx.y * ((MODE == 2) ? 128 : 32);
    const int b0 = blockIdx.z * 128;
    const int tid = threadIdx.x;
    const int wave = tid >> 6, lane = tid & 63;
    const int wm = (wave >> 1) * 64, wn = (wave & 1) * 64;

    __shared__ __align__(16) char smem[49216];
    short* sStage = (short*)smem;             // 3 bufs x 16 KB (8192 shorts each)
    float* gt = (float*)smem;                 // [32][132] f32 epilogue chunk (alias)
    float* pr = (float*)(smem + 49152);

    f32x4 acc[4][4];
#pragma unroll
    for (int i = 0; i < 4; ++i)
#pragma unroll
        for (int j = 0; j < 4; ++j) acc[i][j] = (f32x4){0.f, 0.f, 0.f, 0.f};

    // staging geometry: 1 gload_lds instr = 64 lanes x 16B = 1 KB = 8 rows of 128 B
    const int r8   = lane >> 3;               // row within the instr's 8 rows (== row&7)
    const int cd   = lane & 7;                // dest chunk within row
    const int clog = cd ^ r8;                 // logical chunk (0..3 = A, 4..7 = B)
    const int frow = lane & 15, fkc = lane >> 4;

    // -------- source descriptors --------
    const short* ax; long axs; const short* wxp;
    const short* ah = nullptr; long ahs = 0; const short* whp = nullptr;
    if constexpr (MODE == 0) {
        ax = Xbf + ((size_t)b0 * Tt + t) * Ii; axs = (long)Tt * Ii;
        wxp = Wx + (size_t)f * Gg * Ii;
        if (!FIRST) {
            ah = ysrc + (((size_t)f * Bb + b0) * Tt + (t - 1)) * Hh; ahs = (long)Tt * Hh;
            whp = Wh + (size_t)f * Gg * Hh;
        }
    } else if constexpr (MODE == 1) {
        ax = ysrc + (((size_t)f * Bb + b0) * Tt + t) * Hh; axs = (long)Tt * Hh;
        wxp = Wx + (size_t)f * Gg * Hh;
        if (!FIRST) {
            ah = hsrc + ((size_t)f * Bb + b0) * Hh; ahs = (long)Hh;
            whp = Wh + (size_t)f * Gg * Hh;
        }
    } else {
        ax = hsrc + ((size_t)f * Bb + b0) * Hh; axs = (long)Hh;
        wxp = Wx;
    }

    auto stage = [&](int it, int buf) {
        const short* abase; long as; const short* wbase; int K; int kb;
        if (it < NX) { abase = ax; as = axs; wbase = wxp; K = KX; kb = it * 32; }
        else         { abase = ah; as = ahs; wbase = whp; K = Hh; kb = (it - NX) * 32; }
        short* dst = sStage + buf * 8192;
#pragma unroll
        for (int i = 0; i < 4; ++i) {
            const int inst = wave * 4 + i;
            const int row = inst * 8 + r8;
            const short* srcA = abase + (size_t)row * as + kb + clog * 8;
            const int wr = WG ? ((row >> 5) * Hh + h0 + (row & 31)) : (h0 + row);
            const short* srcB = wbase + (size_t)wr * K + kb + (clog - 4) * 8;
            const short* src = (clog < 4) ? srcA : srcB;
            __builtin_amdgcn_global_load_lds((gas_ptr)(const void*)src,
                (las_ptr)(void*)(dst + inst * 512), 16, 0, 0);
        }
    };

    auto compute = [&](int bufi) {
        const short* bT = sStage + bufi * 8192;
        __builtin_amdgcn_s_setprio(1);
        short8v av[4], bv[4];
#pragma unroll
        for (int i = 0; i < 4; ++i) {
            const int r = wm + i * 16 + frow;
            av[i] = *(const short8v*)&bT[r * 64 + ((fkc ^ (r & 7)) << 3)];
        }
#pragma unroll
        for (int j = 0; j < 4; ++j) {
            const int r = wn + j * 16 + frow;
            bv[j] = *(const short8v*)&bT[r * 64 + (((fkc + 4) ^ (r & 7)) << 3)];
        }
#pragma unroll
        for (int i = 0; i < 4; ++i)
#pragma unroll
            for (int j = 0; j < 4; ++j)
                acc[i][j] = __builtin_amdgcn_mfma_f32_16x16x32_bf16(av[i], bv[j], acc[i][j], 0, 0, 0);
        __builtin_amdgcn_s_setprio(0);
    };

    // preload bias into regs and pin before the pipeline (keeps loop free of stray VMEM)
    float bi[4] = {0.f, 0.f, 0.f, 0.f};
    if constexpr (MODE != 2) {
        const int hl = tid & 31;
#pragma unroll
        for (int g = 0; g < 4; ++g) bi[g] = bias[(size_t)f * Gg + g * Hh + h0 + hl];
        asm volatile("" : "+v"(bi[0]), "+v"(bi[1]), "+v"(bi[2]), "+v"(bi[3]));
    }

    // -------- pipelined K loop (2-deep prefetch, 1 barrier per tile) --------
    stage(0, 0);
    stage(1, 1);
    for (int it = 0; it < NT; ++it) {
        if (it + 1 < NT) asm volatile("s_waitcnt vmcnt(4)" ::: "memory");
        else             asm volatile("s_waitcnt vmcnt(0)" ::: "memory");
        __builtin_amdgcn_s_barrier();
        if (it + 2 < NT) stage(it + 2, (it + 2) % 3);
        __builtin_amdgcn_sched_barrier(0);
        compute(it % 3);
        __builtin_amdgcn_sched_barrier(0);
    }
    __syncthreads();

    // ---- chunked epilogue: 4 chunks of 32 rows through gt [32][132] f32 ----
    if constexpr (MODE != 2) {
        const int hl = tid & 31, bg = tid >> 5;
#pragma unroll
        for (int ch = 0; ch < 4; ++ch) {
            if ((wave >> 1) == (ch >> 1)) {
                const int i0 = (ch & 1) * 2;
#pragma unroll
                for (int i2 = 0; i2 < 2; ++i2) {
                    const int i = i0 + i2;
#pragma unroll
                    for (int j = 0; j < 4; ++j)
#pragma unroll
                        for (int r = 0; r < 4; ++r)
                            gt[(i2 * 16 + (lane >> 4) * 4 + r) * 132 + wn + j * 16 + (lane & 15)] = acc[i][j][r];
                }
            }
            __syncthreads();
#pragma unroll
            for (int ii = 0; ii < 4; ++ii) {
                const int rl = bg * 4 + ii;
                const int b = b0 + ch * 32 + rl;
                const float gi = gt[rl * 132 +      hl] + bi[0];
                const float gf = gt[rl * 132 + 32 + hl] + bi[1];
                const float gg = gt[rl * 132 + 64 + hl] + bi[2];
                const float go = gt[rl * 132 + 96 + hl] + bi[3];
                const size_t cidx = ((size_t)f * Bb + b) * Hh + h0 + hl;
                const float cold = FIRST ? 0.f : cbuf[cidx];
                const float cn = sigmoidf_(gf) * cold + sigmoidf_(gi) * tanhf_(gg);
                const float hv = sigmoidf_(go) * tanhf_(cn);
                cbuf[cidx] = cn;
                const unsigned short hb = f2bf(hv);
                if (MODE == 0)
                    ((unsigned short*)ydst)[(((size_t)f * Bb + b) * Tt + t) * Hh + h0 + hl] = hb;
                else
                    ((unsigned short*)hdst)[cidx] = hb;
            }
            __syncthreads();
        }
    } else {
        const int rr2 = tid >> 3, cb = (tid & 7) * 16;
        float ssum = 0.f, ssq = 0.f;
#pragma unroll
        for (int ch = 0; ch < 4; ++ch) {
            if ((wave >> 1) == (ch >> 1)) {
                const int i0 = (ch & 1) * 2;
#pragma unroll
                for (int i2 = 0; i2 < 2; ++i2) {
                    const int i = i0 + i2;
#pragma unroll
                    for (int j = 0; j < 4; ++j)
#pragma unroll
                        for (int r = 0; r < 4; ++r)
                            gt[(i2 * 16 + (lane >> 4) * 4 + r) * 132 + wn + j * 16 + (lane & 15)] = acc[i][j][r];
                }
            }
            __syncthreads();
            const int b = b0 + ch * 32 + rr2;
            union { unsigned short u[8]; short8v v; } o1, o2;
#pragma unroll
            for (int u = 0; u < 8; ++u) {
                const unsigned short hb = f2bf(gt[rr2 * 132 + cb + u] + bias[h0 + cb + u]);
                const float hv = bf2f(hb);
                ssum += hv; ssq += hv * hv;
                o1.u[u] = hb;
            }
#pragma unroll
            for (int u = 0; u < 8; ++u) {
                const unsigned short hb = f2bf(gt[rr2 * 132 + cb + 8 + u] + bias[h0 + cb + 8 + u]);
                const float hv = bf2f(hb);
                ssum += hv; ssq += hv * hv;
                o2.u[u] = hb;
            }
            unsigned short* dst = htmp + (((size_t)f * Bb + b) * Tt + t) * Hh + h0 + cb;
            *(short8v*)dst = o1.v;
            *(short8v*)(dst + 8) = o2.v;
            __syncthreads();
        }
        // block partial (sum, sumsq) for BN stats
#pragma unroll
        for (int off2 = 32; off2 > 0; off2 >>= 1) {
            ssum += __shfl_down(ssum, off2);
            ssq  += __shfl_down(ssq,  off2);
        }
        if (lane == 0) { pr[wave * 2] = ssum; pr[wave * 2 + 1] = ssq; }
        __syncthreads();
        if (tid == 0) {
            float S = 0.f, Q = 0.f;
#pragma unroll
            for (int w = 0; w < 4; ++w) { S += pr[w * 2]; Q += pr[w * 2 + 1]; }
            const size_t pi = (((size_t)f * Tt + t) * 4 + blockIdx.y) * 8 + blockIdx.z;
            part[pi * 2] = S; part[pi * 2 + 1] = Q;
        }
    }
}

// ---------------- stats combine: mean / rsqrt(var) per (f,t) from 32 partials ----------------
__global__ void stats_combine_kernel(const float* __restrict__ part, float* __restrict__ stats)
{
    const int i = threadIdx.x;
    if (i < Ff * Tt) {
        float s = 0.f, q = 0.f;
        for (int j = 0; j < 32; ++j) { s += part[(i * 32 + j) * 2]; q += part[(i * 32 + j) * 2 + 1]; }
        const float n = (float)((size_t)Bb * Hh);
        const float mean = s / n;
        const float var  = q / n - mean * mean;
        stats[i * 2]     = mean;
        stats[i * 2 + 1] = rsqrtf(var + 1e-5f);
    }
}

// ---------------- Output: out[b,t,f] = sum_o relu(bn(htmp)) * A2[o] + c2 ----------------
__global__ __launch_bounds__(256) void out_kernel(
    const unsigned short* __restrict__ htmp, const float* __restrict__ stats,
    const float* __restrict__ gamma, const float* __restrict__ beta,
    const float* __restrict__ A2, const float* __restrict__ c2,
    float* __restrict__ out)
{
    const int wave = threadIdx.x >> 6;
    const int lane = threadIdx.x & 63;
    const size_t row = (size_t)blockIdx.x * 4 + wave;   // (f*B + b)*T + t
    const int t = (int)(row % Tt);
    const size_t fb = row / Tt;
    const int b = (int)(fb % Bb);
    const int f = (int)(fb / Bb);

    const float mean = stats[(f * Tt + t) * 2];
    const float inv  = stats[(f * Tt + t) * 2 + 1];
    const float ga = gamma[t], be = beta[t];
    const unsigned short* hrow = htmp + row * Hh;

    union { float4 f4; unsigned short u[8]; } hv;
    hv.f4 = *(const float4*)(hrow + lane * 8);
    const float4 a0 = *(const float4*)(A2 + lane * 8);
    const float4 a1 = *(const float4*)(A2 + lane * 8 + 4);
    const float a2v[8] = {a0.x, a0.y, a0.z, a0.w, a1.x, a1.y, a1.z, a1.w};

    float acc = 0.f;
#pragma unroll
    for (int j = 0; j < 8; ++j) {
        const float x = (bf2f(hv.u[j]) - mean) * inv * ga + be;
        acc += fmaxf(x, 0.f) * a2v[j];
    }
#pragma unroll
    for (int off = 32; off > 0; off >>= 1) acc += __shfl_down(acc, off);
    if (lane == 0) out[(size_t)b * Tt * Ff + (size_t)t * Ff + f] = acc + c2[0];
}

extern "C" void kernel_launch(void* const* d_in, const int* in_sizes, int n_in,
                              void* d_out, int out_size, void* d_ws, size_t ws_size,
                              hipStream_t stream) {
    const float* X     = (const float*)d_in[0];
    const float* Wih0  = (const float*)d_in[1];
    const float* Whh0  = (const float*)d_in[2];
    const float* b0p   = (const float*)d_in[3];
    const float* Wih1  = (const float*)d_in[4];
    const float* Whh1  = (const float*)d_in[5];
    const float* b1p   = (const float*)d_in[6];
    const float* A1    = (const float*)d_in[7];
    const float* c1v   = (const float*)d_in[8];
    const float* gamma = (const float*)d_in[9];
    const float* beta  = (const float*)d_in[10];
    const float* A2    = (const float*)d_in[11];
    const float* c2    = (const float*)d_in[12];
    float* out = (float*)d_out;

    // ---- workspace layout (bytes), total ~216 MiB ----
    char* ws = (char*)d_ws;
    size_t off = 0;
    short* Xbf    = (short*)(ws + off); off += (size_t)Bb * Tt * Ii * 2;
    short* Wih0bf = (short*)(ws + off); off += (size_t)Ff * Gg * Ii * 2;
    short* Whh0bf = (short*)(ws + off); off += (size_t)Ff * Gg * Hh * 2;
    short* Wih1bf = (short*)(ws + off); off += (size_t)Ff * Gg * Hh * 2;
    short* Whh1bf = (short*)(ws + off); off += (size_t)Ff * Gg * Hh * 2;
    short* A1bf   = (short*)(ws + off); off += (size_t)Hh * Hh * 2;
    short* ybuf   = (short*)(ws + off); off += (size_t)Ff * Bb * Tt * Hh * 2;
    short* h1A    = (short*)(ws + off); off += (size_t)Ff * Bb * Hh * 2;
    short* h1B    = (short*)(ws + off); off += (size_t)Ff * Bb * Hh * 2;
    float* cbuf   = (float*)(ws + off); off += (size_t)Ff * Bb * Hh * 4;
    float* part   = (float*)(ws + off); off += (size_t)Ff * Tt * 32 * 2 * 4;
    float* stats  = (float*)(ws + off); off += (size_t)Ff * Tt * 2 * 4;

    const dim3 blk(256);
    cvt_kernel<<<dim3((Bb * Tt * Ii / 8 + 255) / 256), blk, 0, stream>>>(X, (unsigned short*)Xbf, Bb * Tt * Ii / 8);
    cvt_kernel<<<dim3((Ff * Gg * Ii / 8 + 255) / 256), blk, 0, stream>>>(Wih0, (unsigned short*)Wih0bf, Ff * Gg * Ii / 8);
    cvt_kernel<<<dim3((Ff * Gg * Hh / 8 + 255) / 256), blk, 0, stream>>>(Whh0, (unsigned short*)Whh0bf, Ff * Gg * Hh / 8);
    cvt_kernel<<<dim3((Ff * Gg * Hh / 8 + 255) / 256), blk, 0, stream>>>(Wih1, (unsigned short*)Wih1bf, Ff * Gg * Hh / 8);
    cvt_kernel<<<dim3((Ff * Gg * Hh / 8 + 255) / 256), blk, 0, stream>>>(Whh1, (unsigned short*)Whh1bf, Ff * Gg * Hh / 8);
    cvt_kernel<<<dim3((Hh * Hh / 8 + 255) / 256), blk, 0, stream>>>(A1, (unsigned short*)A1bf, Hh * Hh / 8);

    const dim3 gstep(Ff, Hh / 32, Bb / 128);   // f fastest -> per-XCD weight residency
    const dim3 gproj(Ff, Hh / 128, Bb / 128);

    // layer 0: all timesteps, writes ybuf[f,b,t,:]
    for (int t = 0; t < Tt; ++t) {
        if (t == 0)
            step_mfma<0, true><<<gstep, blk, 0, stream>>>(Xbf, ybuf, ybuf, nullptr, nullptr,
                Wih0bf, Whh0bf, b0p, cbuf, nullptr, part, t);
        else
            step_mfma<0, false><<<gstep, blk, 0, stream>>>(Xbf, ybuf, ybuf, nullptr, nullptr,
                Wih0bf, Whh0bf, b0p, cbuf, nullptr, part, t);
    }

    // layer 1 + proj: step t reads ybuf slice t; proj overwrites ybuf slice t (stream-ordered)
    for (int t = 0; t < Tt; ++t) {
        short* hn = (t & 1) ? h1A : h1B;
        short* hp = (t & 1) ? h1B : h1A;
        if (t == 0)
            step_mfma<1, true><<<gstep, blk, 0, stream>>>(nullptr, ybuf, nullptr, hp, hn,
                Wih1bf, Whh1bf, b1p, cbuf, nullptr, part, t);
        else
            step_mfma<1, false><<<gstep, blk, 0, stream>>>(nullptr, ybuf, nullptr, hp, hn,
                Wih1bf, Whh1bf, b1p, cbuf, nullptr, part, t);
        step_mfma<2, false><<<gproj, blk, 0, stream>>>(nullptr, nullptr, nullptr, hn, nullptr,
            A1bf, nullptr, c1v, cbuf, (unsigned short*)ybuf, part, t);
    }

    stats_combine_kernel<<<dim3(1), dim3(128), 0, stream>>>(part, stats);
    out_kernel<<<dim3(Ff * Bb * Tt / 4), blk, 0, stream>>>((const unsigned short*)ybuf, stats,
        gamma, beta, A2, c2, out);
    (void)in_sizes; (void)n_in; (void)out_size; (void)ws_size;
}

// Round 8
// 1438.941 us; speedup vs baseline: 4.9225x; 1.1276x over previous
//
#include <hip/hip_runtime.h>
#include <hip/hip_bf16.h>
#include <math.h>

#define Bb 1024
#define Tt 15
#define Ii 256
#define Hh 512
#define Ff 8
#define Gg 2048  // 4*Hh

typedef __attribute__((ext_vector_type(8))) short short8v;
typedef __attribute__((ext_vector_type(4))) float f32x4;

typedef const __attribute__((address_space(1))) void* gas_ptr;
typedef __attribute__((address_space(3))) void* las_ptr;

__device__ __forceinline__ float sigmoidf_(float x) {
    return __builtin_amdgcn_rcpf(1.0f + __expf(-x));
}
__device__ __forceinline__ float tanhf_(float x) {
    x = fminf(fmaxf(x, -15.0f), 15.0f);
    const float e = __expf(2.0f * x);
    return (e - 1.0f) * __builtin_amdgcn_rcpf(e + 1.0f);
}
__device__ __forceinline__ float bf2f(unsigned short u) {
    return __uint_as_float(((unsigned int)u) << 16);
}
__device__ __forceinline__ unsigned short f2bf(float f) {
    unsigned int u = __float_as_uint(f);
    u += 0x7fffu + ((u >> 16) & 1u);   // RNE
    return (unsigned short)(u >> 16);
}

// ---------------- fp32 -> bf16 conversion (n8 = n/8) ----------------
__global__ __launch_bounds__(256) void cvt_kernel(const float* __restrict__ in,
                                                  unsigned short* __restrict__ out, int n8) {
    const int i = blockIdx.x * 256 + threadIdx.x;
    if (i < n8) {
        const float4 v0 = ((const float4*)in)[i * 2];
        const float4 v1 = ((const float4*)in)[i * 2 + 1];
        union { unsigned short u[8]; short8v v; } ob;
        ob.u[0] = f2bf(v0.x); ob.u[1] = f2bf(v0.y); ob.u[2] = f2bf(v0.z); ob.u[3] = f2bf(v0.w);
        ob.u[4] = f2bf(v1.x); ob.u[5] = f2bf(v1.y); ob.u[6] = f2bf(v1.z); ob.u[7] = f2bf(v1.w);
        *(short8v*)&out[(size_t)i * 8] = ob.v;
    }
}

// ---------------- GEMM+epilogue body (R6-proven BK=64 / 2-buf / counted-vmcnt pipeline) ----------------
// MODE 0: layer-0 LSTM step; MODE 1: layer-1 LSTM step; MODE 2: proj (+BN partial stats).
// Tile 128 (batch) x 128 (cols). 4 waves. Per wave per K-tile: 8 global_load_lds(16B);
// steady-state s_waitcnt vmcnt(8); x-phase and h-phase fused into one K pipeline.
template<int MODE>
__device__ __forceinline__ void step_body(
    bool first, int f, int h0, int b0, int t, int hb, int bb,
    const short* ax, long axs, const short* ah, long ahs,
    const short* __restrict__ wxp, const short* __restrict__ whp,
    const float* __restrict__ bias, float* __restrict__ cbuf,
    unsigned short* __restrict__ ydst,    // MODE0: ybuf, MODE1: h1 next, MODE2: htmp(=ybuf)
    float* __restrict__ part, char* smem)
{
    constexpr bool WG = (MODE != 2);
    constexpr int KX = (MODE == 0) ? Ii : Hh;
    constexpr int NX = KX / 64;
    const int NT = (MODE == 2) ? NX : (first ? NX : NX + Hh / 64);

    const int tid = threadIdx.x;
    const int wave = tid >> 6, lane = tid & 63;
    const int wm = (wave >> 1) * 64, wn = (wave & 1) * 64;

    short* sStage = (short*)smem;             // 2 bufs x 16384 shorts (32 KB each)
    float* gt = (float*)smem;                 // [32][132] f32 epilogue chunk (alias)
    float* pr = (float*)(smem + 65536);

    f32x4 acc[4][4];
#pragma unroll
    for (int i = 0; i < 4; ++i)
#pragma unroll
        for (int j = 0; j < 4; ++j) acc[i][j] = (f32x4){0.f, 0.f, 0.f, 0.f};

    // staging geometry: per gload_lds instr: 64 lanes x 16B = 1KB = 8 rows of 128B
    const int srow8 = lane >> 3;
    const int csrc  = (lane & 7) ^ srow8;          // pre-swizzled source chunk
    const int frow  = lane & 15, fks = lane >> 4;

    auto stage = [&](int it, int buf) {
        const short* abase; long as; const short* wbase; int K; int kb;
        if (it < NX) { abase = ax; as = axs; wbase = wxp; K = KX; kb = it * 64; }
        else         { abase = ah; as = ahs; wbase = whp; K = Hh; kb = (it - NX) * 64; }
        short* dA = sStage + buf * 16384;
        short* dB = dA + 8192;
#pragma unroll
        for (int i = 0; i < 4; ++i) {
            const int inst = wave * 4 + i;
            const int row = inst * 8 + srow8;
            const short* srcA = abase + (size_t)row * as + kb + csrc * 8;
            __builtin_amdgcn_global_load_lds((gas_ptr)(const void*)srcA,
                (las_ptr)(void*)(dA + inst * 512), 16, 0, 0);
            const int wr = WG ? ((row >> 5) * Hh + h0 + (row & 31)) : (h0 + row);
            const short* srcB = wbase + (size_t)wr * K + kb + csrc * 8;
            __builtin_amdgcn_global_load_lds((gas_ptr)(const void*)srcB,
                (las_ptr)(void*)(dB + inst * 512), 16, 0, 0);
        }
    };

    auto compute = [&](int buf) {
        const short* bA = sStage + buf * 16384;
        const short* bB = bA + 8192;
        __builtin_amdgcn_s_setprio(1);
#pragma unroll
        for (int ks = 0; ks < 2; ++ks) {
            short8v av[4], bv[4];
#pragma unroll
            for (int i = 0; i < 4; ++i) {
                const int r = wm + i * 16 + frow;
                av[i] = *(const short8v*)&bA[r * 64 + (((fks + ks * 4) ^ (r & 7)) * 8)];
            }
#pragma unroll
            for (int j = 0; j < 4; ++j) {
                const int r = wn + j * 16 + frow;
                bv[j] = *(const short8v*)&bB[r * 64 + (((fks + ks * 4) ^ (r & 7)) * 8)];
            }
#pragma unroll
            for (int i = 0; i < 4; ++i)
#pragma unroll
                for (int j = 0; j < 4; ++j)
                    acc[i][j] = __builtin_amdgcn_mfma_f32_16x16x32_bf16(av[i], bv[j], acc[i][j], 0, 0, 0);
        }
        __builtin_amdgcn_s_setprio(0);
    };

    // preload bias into regs, pin before the pipeline
    float bi[4] = {0.f, 0.f, 0.f, 0.f};
    if constexpr (MODE != 2) {
        const int hl = tid & 31;
#pragma unroll
        for (int g = 0; g < 4; ++g) bi[g] = bias[(size_t)f * Gg + g * Hh + h0 + hl];
        asm volatile("" : "+v"(bi[0]), "+v"(bi[1]), "+v"(bi[2]), "+v"(bi[3]));
    }

    // -------- pipelined K loop --------
    stage(0, 0);
    for (int it = 0; it < NT; ++it) {
        if (it + 1 < NT) {
            stage(it + 1, (it + 1) & 1);
            asm volatile("s_waitcnt vmcnt(8)" ::: "memory");
        } else {
            asm volatile("s_waitcnt vmcnt(0)" ::: "memory");
        }
        __builtin_amdgcn_s_barrier();
        __builtin_amdgcn_sched_barrier(0);
        compute(it & 1);
        __builtin_amdgcn_sched_barrier(0);
        __builtin_amdgcn_s_barrier();
    }

    // ---- chunked epilogue: 4 chunks of 32 rows through gt [32][132] f32 ----
    if constexpr (MODE != 2) {
        const int hl = tid & 31, bg = tid >> 5;
#pragma unroll
        for (int ch = 0; ch < 4; ++ch) {
            if ((wave >> 1) == (ch >> 1)) {
                const int i0 = (ch & 1) * 2;
#pragma unroll
                for (int i2 = 0; i2 < 2; ++i2) {
                    const int i = i0 + i2;
#pragma unroll
                    for (int j = 0; j < 4; ++j)
#pragma unroll
                        for (int r = 0; r < 4; ++r)
                            gt[(i2 * 16 + (lane >> 4) * 4 + r) * 132 + wn + j * 16 + (lane & 15)] = acc[i][j][r];
                }
            }
            __syncthreads();
#pragma unroll
            for (int ii = 0; ii < 4; ++ii) {
                const int rl = bg * 4 + ii;
                const int b = b0 + ch * 32 + rl;
                const float gi = gt[rl * 132 +      hl] + bi[0];
                const float gf = gt[rl * 132 + 32 + hl] + bi[1];
                const float gg = gt[rl * 132 + 64 + hl] + bi[2];
                const float go = gt[rl * 132 + 96 + hl] + bi[3];
                const size_t cidx = ((size_t)f * Bb + b) * Hh + h0 + hl;
                const float cold = first ? 0.f : cbuf[cidx];
                const float cn = sigmoidf_(gf) * cold + sigmoidf_(gi) * tanhf_(gg);
                const float hv = sigmoidf_(go) * tanhf_(cn);
                cbuf[cidx] = cn;
                const unsigned short hb2 = f2bf(hv);
                if (MODE == 0)
                    ydst[(((size_t)f * Bb + b) * Tt + t) * Hh + h0 + hl] = hb2;
                else
                    ydst[cidx] = hb2;
            }
            __syncthreads();
        }
    } else {
        const int rr2 = tid >> 3, cb = (tid & 7) * 16;
        float ssum = 0.f, ssq = 0.f;
#pragma unroll
        for (int ch = 0; ch < 4; ++ch) {
            if ((wave >> 1) == (ch >> 1)) {
                const int i0 = (ch & 1) * 2;
#pragma unroll
                for (int i2 = 0; i2 < 2; ++i2) {
                    const int i = i0 + i2;
#pragma unroll
                    for (int j = 0; j < 4; ++j)
#pragma unroll
                        for (int r = 0; r < 4; ++r)
                            gt[(i2 * 16 + (lane >> 4) * 4 + r) * 132 + wn + j * 16 + (lane & 15)] = acc[i][j][r];
                }
            }
            __syncthreads();
            const int b = b0 + ch * 32 + rr2;
            union { unsigned short u[8]; short8v v; } o1, o2;
#pragma unroll
            for (int u = 0; u < 8; ++u) {
                const unsigned short hb2 = f2bf(gt[rr2 * 132 + cb + u] + bias[h0 + cb + u]);
                const float hv = bf2f(hb2);
                ssum += hv; ssq += hv * hv;
                o1.u[u] = hb2;
            }
#pragma unroll
            for (int u = 0; u < 8; ++u) {
                const unsigned short hb2 = f2bf(gt[rr2 * 132 + cb + 8 + u] + bias[h0 + cb + 8 + u]);
                const float hv = bf2f(hb2);
                ssum += hv; ssq += hv * hv;
                o2.u[u] = hb2;
            }
            unsigned short* dst = ydst + (((size_t)f * Bb + b) * Tt + t) * Hh + h0 + cb;
            *(short8v*)dst = o1.v;
            *(short8v*)(dst + 8) = o2.v;
            __syncthreads();
        }
#pragma unroll
        for (int off2 = 32; off2 > 0; off2 >>= 1) {
            ssum += __shfl_down(ssum, off2);
            ssq  += __shfl_down(ssq,  off2);
        }
        if (lane == 0) { pr[wave * 2] = ssum; pr[wave * 2 + 1] = ssq; }
        __syncthreads();
        if (tid == 0) {
            float S = 0.f, Q = 0.f;
#pragma unroll
            for (int w = 0; w < 4; ++w) { S += pr[w * 2]; Q += pr[w * 2 + 1]; }
            const size_t pi = (((size_t)f * Tt + t) * 4 + hb) * 8 + bb;
            part[pi * 2] = S; part[pi * 2 + 1] = Q;
        }
    }
}

// ---------------- merged per-step kernel: L0(t=d) | L1(t=d-1) | proj(t=d-2) ----------------
// grid = (Ff, 16, 18). z<8: L0 (bb=z); z<16: L1 (bb=z-8); else proj (hb=y&3, bb=(z-16)*4+(y>>2)).
// All cross-role dependencies span a dispatch boundary -> race-free.
__global__ __launch_bounds__(256) void step_merged(
    const short* __restrict__ Xbf, short* __restrict__ ybuf,
    short* __restrict__ h1A, short* __restrict__ h1B,
    const short* __restrict__ W0x, const short* __restrict__ W0h,
    const short* __restrict__ W1x, const short* __restrict__ W1h,
    const short* __restrict__ A1bf,
    const float* __restrict__ b0p, const float* __restrict__ b1p,
    const float* __restrict__ c1v,
    float* __restrict__ c0buf, float* __restrict__ c1buf,
    float* __restrict__ part, int d)
{
    __shared__ __align__(16) char smem[65600];
    const int f = blockIdx.x;
    const int zz = blockIdx.z;

    if (zz < 8) {                       // ---- layer 0, t = d ----
        const int t = d;
        if (t >= Tt) return;
        const int hb = blockIdx.y, h0 = hb * 32, b0 = zz * 128;
        const bool first = (t == 0);
        const short* ax = Xbf + ((size_t)b0 * Tt + t) * Ii;
        const short* ah = first ? nullptr
                                : ybuf + (((size_t)f * Bb + b0) * Tt + (t - 1)) * Hh;
        step_body<0>(first, f, h0, b0, t, hb, zz,
                     ax, (long)Tt * Ii, ah, (long)Tt * Hh,
                     W0x + (size_t)f * Gg * Ii, W0h + (size_t)f * Gg * Hh,
                     b0p, c0buf, (unsigned short*)ybuf, part, smem);
    } else if (zz < 16) {               // ---- layer 1, t = d-1 ----
        const int t = d - 1;
        if (t < 0 || t >= Tt) return;
        const int bb = zz - 8;
        const int hb = blockIdx.y, h0 = hb * 32, b0 = bb * 128;
        const bool first = (t == 0);
        short* hn = (t & 1) ? h1A : h1B;
        const short* hp = (t & 1) ? h1B : h1A;
        const short* ax = ybuf + (((size_t)f * Bb + b0) * Tt + t) * Hh;
        const short* ah = first ? nullptr : hp + ((size_t)f * Bb + b0) * Hh;
        step_body<1>(first, f, h0, b0, t, hb, bb,
                     ax, (long)Tt * Hh, ah, (long)Hh,
                     W1x + (size_t)f * Gg * Hh, W1h + (size_t)f * Gg * Hh,
                     b1p, c1buf, (unsigned short*)hn, part, smem);
    } else {                            // ---- proj, t = d-2 ----
        const int t = d - 2;
        if (t < 0) return;
        const int hb = blockIdx.y & 3, h0 = hb * 128;
        const int bb = (zz - 16) * 4 + (blockIdx.y >> 2), b0 = bb * 128;
        const short* hn = (t & 1) ? h1A : h1B;
        const short* ax = hn + ((size_t)f * Bb + b0) * Hh;
        step_body<2>(false, f, h0, b0, t, hb, bb,
                     ax, (long)Hh, nullptr, 0L,
                     A1bf, nullptr,
                     c1v, nullptr, (unsigned short*)ybuf, part, smem);
    }
}

// ---------------- stats combine: mean / rsqrt(var) per (f,t) from 32 partials ----------------
__global__ void stats_combine_kernel(const float* __restrict__ part, float* __restrict__ stats)
{
    const int i = threadIdx.x;
    if (i < Ff * Tt) {
        float s = 0.f, q = 0.f;
        for (int j = 0; j < 32; ++j) { s += part[(i * 32 + j) * 2]; q += part[(i * 32 + j) * 2 + 1]; }
        const float n = (float)((size_t)Bb * Hh);
        const float mean = s / n;
        const float var  = q / n - mean * mean;
        stats[i * 2]     = mean;
        stats[i * 2 + 1] = rsqrtf(var + 1e-5f);
    }
}

// ---------------- Output: out[b,t,f] = sum_o relu(bn(htmp)) * A2[o] + c2 ----------------
__global__ __launch_bounds__(256) void out_kernel(
    const unsigned short* __restrict__ htmp, const float* __restrict__ stats,
    const float* __restrict__ gamma, const float* __restrict__ beta,
    const float* __restrict__ A2, const float* __restrict__ c2,
    float* __restrict__ out)
{
    const int wave = threadIdx.x >> 6;
    const int lane = threadIdx.x & 63;
    const size_t row = (size_t)blockIdx.x * 4 + wave;   // (f*B + b)*T + t
    const int t = (int)(row % Tt);
    const size_t fb = row / Tt;
    const int b = (int)(fb % Bb);
    const int f = (int)(fb / Bb);

    const float mean = stats[(f * Tt + t) * 2];
    const float inv  = stats[(f * Tt + t) * 2 + 1];
    const float ga = gamma[t], be = beta[t];
    const unsigned short* hrow = htmp + row * Hh;

    union { float4 f4; unsigned short u[8]; } hv;
    hv.f4 = *(const float4*)(hrow + lane * 8);
    const float4 a0 = *(const float4*)(A2 + lane * 8);
    const float4 a1 = *(const float4*)(A2 + lane * 8 + 4);
    const float a2v[8] = {a0.x, a0.y, a0.z, a0.w, a1.x, a1.y, a1.z, a1.w};

    float acc = 0.f;
#pragma unroll
    for (int j = 0; j < 8; ++j) {
        const float x = (bf2f(hv.u[j]) - mean) * inv * ga + be;
        acc += fmaxf(x, 0.f) * a2v[j];
    }
#pragma unroll
    for (int off = 32; off > 0; off >>= 1) acc += __shfl_down(acc, off);
    if (lane == 0) out[(size_t)b * Tt * Ff + (size_t)t * Ff + f] = acc + c2[0];
}

extern "C" void kernel_launch(void* const* d_in, const int* in_sizes, int n_in,
                              void* d_out, int out_size, void* d_ws, size_t ws_size,
                              hipStream_t stream) {
    const float* X     = (const float*)d_in[0];
    const float* Wih0  = (const float*)d_in[1];
    const float* Whh0  = (const float*)d_in[2];
    const float* b0p   = (const float*)d_in[3];
    const float* Wih1  = (const float*)d_in[4];
    const float* Whh1  = (const float*)d_in[5];
    const float* b1p   = (const float*)d_in[6];
    const float* A1    = (const float*)d_in[7];
    const float* c1v   = (const float*)d_in[8];
    const float* gamma = (const float*)d_in[9];
    const float* beta  = (const float*)d_in[10];
    const float* A2    = (const float*)d_in[11];
    const float* c2    = (const float*)d_in[12];
    float* out = (float*)d_out;

    // ---- workspace layout (bytes), total ~233 MiB ----
    char* ws = (char*)d_ws;
    size_t off = 0;
    short* Xbf    = (short*)(ws + off); off += (size_t)Bb * Tt * Ii * 2;
    short* Wih0bf = (short*)(ws + off); off += (size_t)Ff * Gg * Ii * 2;
    short* Whh0bf = (short*)(ws + off); off += (size_t)Ff * Gg * Hh * 2;
    short* Wih1bf = (short*)(ws + off); off += (size_t)Ff * Gg * Hh * 2;
    short* Whh1bf = (short*)(ws + off); off += (size_t)Ff * Gg * Hh * 2;
    short* A1bf   = (short*)(ws + off); off += (size_t)Hh * Hh * 2;
    short* ybuf   = (short*)(ws + off); off += (size_t)Ff * Bb * Tt * Hh * 2;
    short* h1A    = (short*)(ws + off); off += (size_t)Ff * Bb * Hh * 2;
    short* h1B    = (short*)(ws + off); off += (size_t)Ff * Bb * Hh * 2;
    float* c0buf  = (float*)(ws + off); off += (size_t)Ff * Bb * Hh * 4;
    float* c1buf  = (float*)(ws + off); off += (size_t)Ff * Bb * Hh * 4;
    float* part   = (float*)(ws + off); off += (size_t)Ff * Tt * 32 * 2 * 4;
    float* stats  = (float*)(ws + off); off += (size_t)Ff * Tt * 2 * 4;

    const dim3 blk(256);
    cvt_kernel<<<dim3((Bb * Tt * Ii / 8 + 255) / 256), blk, 0, stream>>>(X, (unsigned short*)Xbf, Bb * Tt * Ii / 8);
    cvt_kernel<<<dim3((Ff * Gg * Ii / 8 + 255) / 256), blk, 0, stream>>>(Wih0, (unsigned short*)Wih0bf, Ff * Gg * Ii / 8);
    cvt_kernel<<<dim3((Ff * Gg * Hh / 8 + 255) / 256), blk, 0, stream>>>(Whh0, (unsigned short*)Whh0bf, Ff * Gg * Hh / 8);
    cvt_kernel<<<dim3((Ff * Gg * Hh / 8 + 255) / 256), blk, 0, stream>>>(Wih1, (unsigned short*)Wih1bf, Ff * Gg * Hh / 8);
    cvt_kernel<<<dim3((Ff * Gg * Hh / 8 + 255) / 256), blk, 0, stream>>>(Whh1, (unsigned short*)Whh1bf, Ff * Gg * Hh / 8);
    cvt_kernel<<<dim3((Hh * Hh / 8 + 255) / 256), blk, 0, stream>>>(A1, (unsigned short*)A1bf, Hh * Hh / 8);

    // software-pipelined role-merged steps: d=0..16
    const dim3 gmerged(Ff, 16, 18);
    for (int d = 0; d <= Tt + 1; ++d) {
        step_merged<<<gmerged, blk, 0, stream>>>(
            Xbf, ybuf, h1A, h1B,
            Wih0bf, Whh0bf, Wih1bf, Whh1bf, A1bf,
            b0p, b1p, c1v, c0buf, c1buf, part, d);
    }

    stats_combine_kernel<<<dim3(1), dim3(128), 0, stream>>>(part, stats);
    out_kernel<<<dim3(Ff * Bb * Tt / 4), blk, 0, stream>>>((const unsigned short*)ybuf, stats,
        gamma, beta, A2, c2, out);
    (void)in_sizes; (void)n_in; (void)out_size; (void)ws_size;
}